// Round 3
// baseline (667.730 us; speedup 1.0000x reference)
//
#include <hip/hip_runtime.h>

#define NN 50000
#define HH 8
#define ALPHA 0.2f

__device__ __forceinline__ float elu_f(float x) {
  return x > 0.f ? x : __expf(x) - 1.f;
}

__device__ __forceinline__ unsigned short f2bf(float f) {
  unsigned int u = __float_as_uint(f);
  unsigned int r = (u + 0x7fffu + ((u >> 16) & 1u)) >> 16;
  return (unsigned short)r;
}

// ---------------- CSR build ----------------
__global__ void hist_kernel(const int* __restrict__ src, int* __restrict__ cnt, int E) {
  int e = blockIdx.x * blockDim.x + threadIdx.x;
  if (e < E) atomicAdd(&cnt[src[e]], 1);
}

__global__ __launch_bounds__(1024) void scan_blocks_kernel(const int* __restrict__ cnt,
    int* __restrict__ tmp, int* __restrict__ bsum, int n) {
  __shared__ int sh[1024];
  int i = blockIdx.x * 1024 + threadIdx.x;
  int v = (i < n) ? cnt[i] : 0;
  sh[threadIdx.x] = v;
  __syncthreads();
  for (int off = 1; off < 1024; off <<= 1) {
    int t = (threadIdx.x >= off) ? sh[threadIdx.x - off] : 0;
    __syncthreads();
    sh[threadIdx.x] += t;
    __syncthreads();
  }
  if (i < n) tmp[i] = sh[threadIdx.x] - v;          // exclusive within block
  if (threadIdx.x == 1023) bsum[blockIdx.x] = sh[1023];
}

__global__ __launch_bounds__(64) void scan_top_kernel(const int* __restrict__ bsum,
    int* __restrict__ boffs, int nb) {
  int L = threadIdx.x;
  int v = (L < nb) ? bsum[L] : 0;
  int incl = v;
#pragma unroll
  for (int off = 1; off < 64; off <<= 1) {
    int t = __shfl_up(incl, off, 64);
    if (L >= off) incl += t;
  }
  if (L < nb) boffs[L] = incl - v;                  // exclusive block offsets
}

__global__ __launch_bounds__(1024) void scan_apply_kernel(const int* __restrict__ tmp,
    const int* __restrict__ boffs, int* __restrict__ row_ptr, int* __restrict__ nxt,
    int n, int E) {
  int i = blockIdx.x * 1024 + threadIdx.x;
  if (i < n) {
    int s = tmp[i] + boffs[blockIdx.x];
    row_ptr[i] = s;
    nxt[i] = s;
  }
  if (i == 0) row_ptr[n] = E;
}

__global__ void scatter_kernel(const int* __restrict__ src, const int* __restrict__ dst,
                               int* __restrict__ nxt, int* __restrict__ col, int E) {
  int e = blockIdx.x * blockDim.x + threadIdx.x;
  if (e < E) {
    int p = atomicAdd(&nxt[src[e]], 1);
    col[p] = dst[e];
  }
}

// ---------------- fused GEMM + attention-score epilogue ----------------
// C[y][r][c] = X[r,:K] . B_all[y][:,c]   (c in [0,64))
// ss[y*N+r] = C[y][r][:] . Aatt[y][:64] ; sd[y*N+r] = C[y][r][:] . Aatt[y][64:]
// Table written as bf16 [H][N][64]; scores stay fp32.
__global__ __launch_bounds__(256) void gemm_fused_kernel(const float* __restrict__ X,
    const float* __restrict__ B_all, const float* __restrict__ Aatt,
    unsigned short* __restrict__ Cout, float* __restrict__ ss, float* __restrict__ sd,
    int N, int K) {
  __shared__ float As[16][136];   // [k][row], 128 rows + pad
  __shared__ float Bs[16][68];    // [k][col], 64 cols + pad
  const int y = blockIdx.y;
  const float* B = B_all + (size_t)y * K * 64;
  int r0 = blockIdx.x * 128;
  int tx = threadIdx.x & 15;      // col quad
  int ty = threadIdx.x >> 4;      // row octet
  float acc[8][4];
#pragma unroll
  for (int i = 0; i < 8; ++i)
#pragma unroll
    for (int j = 0; j < 4; ++j) acc[i][j] = 0.f;

  for (int k0 = 0; k0 < K; k0 += 16) {
#pragma unroll
    for (int it = 0; it < 2; ++it) {        // stage A: 128 rows x 16 k
      int l = threadIdx.x + it * 256;       // 0..511
      int row = l >> 2;
      int kq = (l & 3) << 2;
      int r = r0 + row;
      float4 v = make_float4(0.f, 0.f, 0.f, 0.f);
      if (r < N) v = *(const float4*)(X + (size_t)r * K + k0 + kq);
      As[kq][row] = v.x; As[kq + 1][row] = v.y; As[kq + 2][row] = v.z; As[kq + 3][row] = v.w;
    }
    {                                       // stage B: 16 k x 64 cols
      int kk = threadIdx.x >> 4;
      int c = (threadIdx.x & 15) << 2;
      *(float4*)&Bs[kk][c] = *(const float4*)(B + (size_t)(k0 + kk) * 64 + c);
    }
    __syncthreads();
#pragma unroll
    for (int kk = 0; kk < 16; ++kk) {
      float4 b4 = *(const float4*)&Bs[kk][tx << 2];
      float4 a0 = *(const float4*)&As[kk][ty << 3];
      float4 a1 = *(const float4*)&As[kk][(ty << 3) + 4];
      float av[8] = {a0.x, a0.y, a0.z, a0.w, a1.x, a1.y, a1.z, a1.w};
      float bv[4] = {b4.x, b4.y, b4.z, b4.w};
#pragma unroll
      for (int i = 0; i < 8; ++i)
#pragma unroll
        for (int j = 0; j < 4; ++j) acc[i][j] += av[i] * bv[j];
    }
    __syncthreads();
  }

  // epilogue: scores + bf16 table write
  float4 as4 = *(const float4*)(Aatt + y * 128 + (tx << 2));
  float4 ad4 = *(const float4*)(Aatt + y * 128 + 64 + (tx << 2));
  size_t yN = (size_t)y * N;
#pragma unroll
  for (int i = 0; i < 8; ++i) {
    int r = r0 + (ty << 3) + i;
    float ps = acc[i][0] * as4.x + acc[i][1] * as4.y + acc[i][2] * as4.z + acc[i][3] * as4.w;
    float pd = acc[i][0] * ad4.x + acc[i][1] * ad4.y + acc[i][2] * ad4.z + acc[i][3] * ad4.w;
#pragma unroll
    for (int off = 1; off < 16; off <<= 1) {
      ps += __shfl_xor(ps, off, 64);
      pd += __shfl_xor(pd, off, 64);
    }
    if (r < N) {
      if (tx == 0) { ss[yN + r] = ps; sd[yN + r] = pd; }
      ushort4 pk;
      pk.x = f2bf(acc[i][0]); pk.y = f2bf(acc[i][1]);
      pk.z = f2bf(acc[i][2]); pk.w = f2bf(acc[i][3]);
      *(ushort4*)(Cout + (yN + r) * 64 + (tx << 2)) = pk;
    }
  }
}

// ---------------- aggregation: lane L owns feature L, readlane broadcast ----------------
// grid (ceil(N/4), H), 256 thr = 4 waves, one wave per (node, head).
// table: bf16 [H][N][64]; ss/sd: fp32 [H][N]; out[n*out_stride + h*64 + L] = elu(num/rs).
__global__ __launch_bounds__(256) void agg_kernel(const unsigned short* __restrict__ table,
    const float* __restrict__ ss, const float* __restrict__ sd,
    const int* __restrict__ row_ptr, const int* __restrict__ col,
    float* __restrict__ outp, int out_stride, int N) {
  int h = blockIdx.y;
  int wid = threadIdx.x >> 6, L = threadIdx.x & 63;
  int n = blockIdx.x * 4 + wid;
  if (n >= N) return;
  const size_t hN = (size_t)h * N;
  const unsigned short* tab = table + hN * 64;
  const float* sdh = sd + hN;
  float ssn = ss[hN + n];
  int k0 = row_ptr[n];
  int deg = row_ptr[n + 1] - k0;
  float acc = 0.f, rs = 0.f;

  for (int c0 = 0; c0 < deg; c0 += 64) {
    int j = c0 + L;
    int d = 0;
    float e = 0.f;
    if (j < deg) {
      d = col[k0 + j];
      float s = ssn + sdh[d];
      e = __expf(-fmaxf(s, ALPHA * s));     // -leaky(s): max(s,.2s)=leaky for both signs
    }
    rs += e;
    int m = min(64, deg - c0);
    for (int jj = 0; jj < m; jj += 8) {     // slots past m have e=0, d=0 (row 0, L1-hot)
      float vals[8], ee[8];
#pragma unroll
      for (int t = 0; t < 8; ++t) {
        int dg = __builtin_amdgcn_readlane(d, jj + t);            // SGPR
        ee[t] = __uint_as_float(
            (unsigned)__builtin_amdgcn_readlane(__float_as_uint(e), jj + t));
        vals[t] = __uint_as_float(((unsigned)tab[(size_t)dg * 64 + L]) << 16);
      }
#pragma unroll
      for (int t = 0; t < 8; ++t) acc += ee[t] * vals[t];
    }
  }
#pragma unroll
  for (int off = 1; off < 64; off <<= 1) rs += __shfl_xor(rs, off, 64);
  outp[(size_t)n * out_stride + h * 64 + L] = elu_f(acc / rs);
}

// ---------------- final classifier ----------------
__global__ __launch_bounds__(256) void final_kernel(const float* __restrict__ xo,
    const float* __restrict__ mlp_w, const float* __restrict__ mlp_b,
    float* __restrict__ out, int total) {
  __shared__ float wsh[40 * 65];
  __shared__ float bsh[40];
  for (int i = threadIdx.x; i < 40 * 64; i += 256) wsh[(i >> 6) * 65 + (i & 63)] = mlp_w[i];
  if (threadIdx.x < 40) bsh[threadIdx.x] = mlp_b[threadIdx.x];
  __syncthreads();
  int idx = blockIdx.x * 256 + threadIdx.x;
  if (idx >= total) return;
  int n = idx / 40, c = idx - n * 40;
  const float* xr = xo + (size_t)n * 64;
  const float* wr = wsh + c * 65;
  float acc = bsh[c];
#pragma unroll
  for (int j = 0; j < 64; ++j) acc += xr[j] * wr[j];
  out[idx] = acc;
}

extern "C" void kernel_launch(void* const* d_in, const int* in_sizes, int n_in,
                              void* d_out, int out_size, void* d_ws, size_t ws_size,
                              hipStream_t stream) {
  (void)n_in; (void)out_size; (void)ws_size;
  const float* x  = (const float*)d_in[0];
  const int*   ei = (const int*)d_in[1];
  const float* W  = (const float*)d_in[2];
  const float* a  = (const float*)d_in[3];
  const float* Wo = (const float*)d_in[4];
  const float* ao = (const float*)d_in[5];
  const float* mw = (const float*)d_in[6];
  const float* mb = (const float*)d_in[7];
  float* out = (float*)d_out;

  const int N = NN;
  const int E = in_sizes[1] / 2;
  const int* src = ei;
  const int* dst = ei + E;

  char* ws = (char*)d_ws;
  size_t off = 0;
  auto alloc = [&](size_t bytes) {
    char* p = ws + off;
    off = (off + bytes + 255) & ~(size_t)255;
    return p;
  };
  unsigned short* h1b = (unsigned short*)alloc((size_t)HH * N * 64 * 2); // 51.2 MB
  float* ss1     = (float*)alloc((size_t)HH * N * 4);
  float* sd1     = (float*)alloc((size_t)HH * N * 4);
  float* xc      = (float*)alloc((size_t)N * 512 * 4);                   // 102.4 MB
  unsigned short* h2b = (unsigned short*)alloc((size_t)N * 64 * 2);      // 6.4 MB
  float* ss2     = (float*)alloc((size_t)N * 4);
  float* sd2     = (float*)alloc((size_t)N * 4);
  float* xo      = (float*)alloc((size_t)N * 64 * 4);
  int*   row_ptr = (int*)  alloc((size_t)(N + 1) * 4);
  int*   nxt     = (int*)  alloc((size_t)N * 4);
  int*   cnt     = (int*)  alloc((size_t)N * 4);
  int*   tmp     = (int*)  alloc((size_t)N * 4);
  int*   bsum    = (int*)  alloc(64 * 4);
  int*   boffs   = (int*)  alloc(64 * 4);
  int*   colv    = (int*)  alloc((size_t)E * 4);

  int eb = (E + 255) / 256;
  int nb1024 = (N + 1023) / 1024;   // 49

  hipMemsetAsync(cnt, 0, (size_t)N * 4, stream);
  hipLaunchKernelGGL(hist_kernel, dim3(eb), dim3(256), 0, stream, src, cnt, E);
  hipLaunchKernelGGL(scan_blocks_kernel, dim3(nb1024), dim3(1024), 0, stream, cnt, tmp, bsum, N);
  hipLaunchKernelGGL(scan_top_kernel, dim3(1), dim3(64), 0, stream, bsum, boffs, nb1024);
  hipLaunchKernelGGL(scan_apply_kernel, dim3(nb1024), dim3(1024), 0, stream, tmp, boffs, row_ptr, nxt, N, E);
  hipLaunchKernelGGL(scatter_kernel, dim3(eb), dim3(256), 0, stream, src, dst, nxt, colv, E);

  // layer 1: h1b(bf16, head-major) + scores, then aggregate -> xc
  hipLaunchKernelGGL(gemm_fused_kernel, dim3((N + 127) / 128, HH), dim3(256), 0, stream,
                     x, W, a, h1b, ss1, sd1, N, 256);
  hipLaunchKernelGGL(agg_kernel, dim3((N + 3) / 4, HH), dim3(256), 0, stream,
                     h1b, ss1, sd1, row_ptr, colv, xc, 512, N);

  // layer 2: h2b = bf16(xc @ Wo) + scores, aggregate -> xo
  hipLaunchKernelGGL(gemm_fused_kernel, dim3((N + 127) / 128, 1), dim3(256), 0, stream,
                     xc, Wo, ao, h2b, ss2, sd2, N, 512);
  hipLaunchKernelGGL(agg_kernel, dim3((N + 3) / 4, 1), dim3(256), 0, stream,
                     h2b, ss2, sd2, row_ptr, colv, xo, 64, N);

  // classifier
  hipLaunchKernelGGL(final_kernel, dim3((N * 40 + 255) / 256), dim3(256), 0, stream,
                     xo, mw, mb, out, N * 40);
}

// Round 4
// 645.688 us; speedup vs baseline: 1.0341x; 1.0341x over previous
//
#include <hip/hip_runtime.h>

#define NN 50000
#define HH 8
#define ALPHA 0.2f

__device__ __forceinline__ float elu_f(float x) {
  return x > 0.f ? x : __expf(x) - 1.f;
}

__device__ __forceinline__ unsigned short f2bf(float f) {
  unsigned int u = __float_as_uint(f);
  unsigned int r = (u + 0x7fffu + ((u >> 16) & 1u)) >> 16;
  return (unsigned short)r;
}

// ---------------- CSR build ----------------
__global__ void hist_kernel(const int* __restrict__ src, int* __restrict__ cnt, int E) {
  int e = blockIdx.x * blockDim.x + threadIdx.x;
  if (e < E) atomicAdd(&cnt[src[e]], 1);
}

__global__ __launch_bounds__(1024) void scan_blocks_kernel(const int* __restrict__ cnt,
    int* __restrict__ tmp, int* __restrict__ bsum, int n) {
  __shared__ int sh[1024];
  int i = blockIdx.x * 1024 + threadIdx.x;
  int v = (i < n) ? cnt[i] : 0;
  sh[threadIdx.x] = v;
  __syncthreads();
  for (int off = 1; off < 1024; off <<= 1) {
    int t = (threadIdx.x >= off) ? sh[threadIdx.x - off] : 0;
    __syncthreads();
    sh[threadIdx.x] += t;
    __syncthreads();
  }
  if (i < n) tmp[i] = sh[threadIdx.x] - v;          // exclusive within block
  if (threadIdx.x == 1023) bsum[blockIdx.x] = sh[1023];
}

__global__ __launch_bounds__(64) void scan_top_kernel(const int* __restrict__ bsum,
    int* __restrict__ boffs, int nb) {
  int L = threadIdx.x;
  int v = (L < nb) ? bsum[L] : 0;
  int incl = v;
#pragma unroll
  for (int off = 1; off < 64; off <<= 1) {
    int t = __shfl_up(incl, off, 64);
    if (L >= off) incl += t;
  }
  if (L < nb) boffs[L] = incl - v;                  // exclusive block offsets
}

__global__ __launch_bounds__(1024) void scan_apply_kernel(const int* __restrict__ tmp,
    const int* __restrict__ boffs, int* __restrict__ row_ptr, int* __restrict__ nxt,
    int n, int E) {
  int i = blockIdx.x * 1024 + threadIdx.x;
  if (i < n) {
    int s = tmp[i] + boffs[blockIdx.x];
    row_ptr[i] = s;
    nxt[i] = s;
  }
  if (i == 0) row_ptr[n] = E;
}

__global__ void scatter_kernel(const int* __restrict__ src, const int* __restrict__ dst,
                               int* __restrict__ nxt, int* __restrict__ col, int E) {
  int e = blockIdx.x * blockDim.x + threadIdx.x;
  if (e < E) {
    int p = atomicAdd(&nxt[src[e]], 1);
    col[p] = dst[e];
  }
}

// ---------------- fused GEMM + attention-score epilogue ----------------
// C[r, y*64+c] = X[r,:K] . B_all[y][:,c]; table bf16 at Cout[r*tab_stride + y*64 + c];
// scores fp32 at ss/sd[r*score_stride + y].
__global__ __launch_bounds__(256) void gemm_fused_kernel(const float* __restrict__ X,
    const float* __restrict__ B_all, const float* __restrict__ Aatt,
    unsigned short* __restrict__ Cout, float* __restrict__ ss, float* __restrict__ sd,
    int N, int K, int tab_stride, int score_stride) {
  __shared__ float As[16][136];   // [k][row], 128 rows + pad
  __shared__ float Bs[16][68];    // [k][col], 64 cols + pad
  const int y = blockIdx.y;
  const float* B = B_all + (size_t)y * K * 64;
  int r0 = blockIdx.x * 128;
  int tx = threadIdx.x & 15;      // col quad
  int ty = threadIdx.x >> 4;      // row octet
  float acc[8][4];
#pragma unroll
  for (int i = 0; i < 8; ++i)
#pragma unroll
    for (int j = 0; j < 4; ++j) acc[i][j] = 0.f;

  for (int k0 = 0; k0 < K; k0 += 16) {
#pragma unroll
    for (int it = 0; it < 2; ++it) {        // stage A: 128 rows x 16 k
      int l = threadIdx.x + it * 256;       // 0..511
      int row = l >> 2;
      int kq = (l & 3) << 2;
      int r = r0 + row;
      float4 v = make_float4(0.f, 0.f, 0.f, 0.f);
      if (r < N) v = *(const float4*)(X + (size_t)r * K + k0 + kq);
      As[kq][row] = v.x; As[kq + 1][row] = v.y; As[kq + 2][row] = v.z; As[kq + 3][row] = v.w;
    }
    {                                       // stage B: 16 k x 64 cols
      int kk = threadIdx.x >> 4;
      int c = (threadIdx.x & 15) << 2;
      *(float4*)&Bs[kk][c] = *(const float4*)(B + (size_t)(k0 + kk) * 64 + c);
    }
    __syncthreads();
#pragma unroll
    for (int kk = 0; kk < 16; ++kk) {
      float4 b4 = *(const float4*)&Bs[kk][tx << 2];
      float4 a0 = *(const float4*)&As[kk][ty << 3];
      float4 a1 = *(const float4*)&As[kk][(ty << 3) + 4];
      float av[8] = {a0.x, a0.y, a0.z, a0.w, a1.x, a1.y, a1.z, a1.w};
      float bv[4] = {b4.x, b4.y, b4.z, b4.w};
#pragma unroll
      for (int i = 0; i < 8; ++i)
#pragma unroll
        for (int j = 0; j < 4; ++j) acc[i][j] += av[i] * bv[j];
    }
    __syncthreads();
  }

  // epilogue: scores + bf16 table write
  float4 as4 = *(const float4*)(Aatt + y * 128 + (tx << 2));
  float4 ad4 = *(const float4*)(Aatt + y * 128 + 64 + (tx << 2));
#pragma unroll
  for (int i = 0; i < 8; ++i) {
    int r = r0 + (ty << 3) + i;
    float ps = acc[i][0] * as4.x + acc[i][1] * as4.y + acc[i][2] * as4.z + acc[i][3] * as4.w;
    float pd = acc[i][0] * ad4.x + acc[i][1] * ad4.y + acc[i][2] * ad4.z + acc[i][3] * ad4.w;
#pragma unroll
    for (int off = 1; off < 16; off <<= 1) {
      ps += __shfl_xor(ps, off, 64);
      pd += __shfl_xor(pd, off, 64);
    }
    if (r < N) {
      if (tx == 0) { ss[(size_t)r * score_stride + y] = ps; sd[(size_t)r * score_stride + y] = pd; }
      ushort4 pk;
      pk.x = f2bf(acc[i][0]); pk.y = f2bf(acc[i][1]);
      pk.z = f2bf(acc[i][2]); pk.w = f2bf(acc[i][3]);
      *(ushort4*)(Cout + (size_t)r * tab_stride + y * 64 + (tx << 2)) = pk;
    }
  }
}

// ---------------- layer-1 aggregation: wave per node, all 8 heads fused ----------------
// table: bf16 [N][512] (head-major columns); ss/sd: fp32 [N][8].
// Lane L: head h=L>>3, feature block b=L&7 (8 feats). One dwordx4 = whole 1KB edge row.
__global__ __launch_bounds__(256) void agg1_kernel(const unsigned short* __restrict__ table,
    const float* __restrict__ ss, const float* __restrict__ sd,
    const int* __restrict__ row_ptr, const int* __restrict__ col,
    float* __restrict__ xc, int N) {
  int wid = threadIdx.x >> 6, L = threadIdx.x & 63;
  int n = blockIdx.x * 4 + wid;
  if (n >= N) return;
  int h = L >> 3;
  int b = L & 7;
  int srcsel = h << 3;                       // base lane of this head's weight group
  float ssn = ss[n * 8 + h];
  int k0 = row_ptr[n], deg = row_ptr[n + 1] - k0;
  float acc[8];
#pragma unroll
  for (int t = 0; t < 8; ++t) acc[t] = 0.f;
  float rs = 0.f;

  for (int c0 = 0; c0 < deg; c0 += 64) {
    int j = c0 + L;
    int d_l = (j < deg) ? col[k0 + j] : 0;
    int m = min(64, deg - c0);
    for (int g = 0; g < m; g += 8) {
      // weights: lane (h'*8+b') computes e for (edge g+b', head h')
      int eoff = g + b;
      int de = __shfl(d_l, eoff, 64);
      float sv = sd[(size_t)de * 8 + h];
      float s = ssn + sv;
      float e = __expf(-fmaxf(s, ALPHA * s));
      if (eoff >= m) e = 0.f;
      rs += e;
      // gather rows for edges g..g+gm-1; prefetch 1 deep
      int gm = min(8, m - g);
      int d0 = __builtin_amdgcn_readlane(d_l, g);
      uint4 rv = *((const uint4*)(table + (size_t)d0 * 512) + L);
      for (int jj = 0; jj < gm; ++jj) {
        uint4 cur = rv;
        if (jj + 1 < gm) {
          int dn = __builtin_amdgcn_readlane(d_l, g + jj + 1);
          rv = *((const uint4*)(table + (size_t)dn * 512) + L);
        }
        float ew = __shfl(e, srcsel + jj, 64);
        const unsigned int* up = (const unsigned int*)&cur;
#pragma unroll
        for (int w = 0; w < 4; ++w) {
          acc[2 * w]     += ew * __uint_as_float(up[w] << 16);
          acc[2 * w + 1] += ew * __uint_as_float(up[w] & 0xffff0000u);
        }
      }
    }
  }
  // rs: sum over the 8 lanes of this head group (xor of low 3 bits stays in group)
  rs += __shfl_xor(rs, 1, 64);
  rs += __shfl_xor(rs, 2, 64);
  rs += __shfl_xor(rs, 4, 64);
  float inv = 1.f / rs;
  float o[8];
#pragma unroll
  for (int t = 0; t < 8; ++t) o[t] = elu_f(acc[t] * inv);
  float4* p = (float4*)(xc + (size_t)n * 512 + L * 8);
  p[0] = make_float4(o[0], o[1], o[2], o[3]);
  p[1] = make_float4(o[4], o[5], o[6], o[7]);
}

// ---------------- layer-2 aggregation: wave per node, 1 head, lane = feature ----------------
// table: bf16 [N][64]; ss/sd fp32 [N].
__global__ __launch_bounds__(256) void agg2_kernel(const unsigned short* __restrict__ table,
    const float* __restrict__ ss, const float* __restrict__ sd,
    const int* __restrict__ row_ptr, const int* __restrict__ col,
    float* __restrict__ xo, int N) {
  int wid = threadIdx.x >> 6, L = threadIdx.x & 63;
  int n = blockIdx.x * 4 + wid;
  if (n >= N) return;
  float ssn = ss[n];
  int k0 = row_ptr[n], deg = row_ptr[n + 1] - k0;
  float acc = 0.f, rs = 0.f;
  const char* base = (const char*)table;

  for (int c0 = 0; c0 < deg; c0 += 64) {
    int j = c0 + L;
    int d_l = 0;
    float e_l = 0.f;
    if (j < deg) {
      d_l = col[k0 + j];
      float s = ssn + sd[d_l];
      e_l = __expf(-fmaxf(s, ALPHA * s));
    }
    rs += e_l;
    int m = min(64, deg - c0);
    int off_l = d_l << 7;                    // row byte offset (64 * 2B)
    int so = __builtin_amdgcn_readlane(off_l, 0);
    unsigned hv = *(const unsigned short*)(base + so + L * 2);
    for (int jj = 0; jj < m; ++jj) {
      unsigned cur = hv;
      if (jj + 1 < m) {
        so = __builtin_amdgcn_readlane(off_l, jj + 1);
        hv = *(const unsigned short*)(base + so + L * 2);
      }
      float ew = __uint_as_float(
          (unsigned)__builtin_amdgcn_readlane(__float_as_uint(e_l), jj));
      acc += ew * __uint_as_float(cur << 16);
    }
  }
#pragma unroll
  for (int off = 1; off < 64; off <<= 1) rs += __shfl_xor(rs, off, 64);
  xo[(size_t)n * 64 + L] = elu_f(acc / rs);
}

// ---------------- final classifier ----------------
__global__ __launch_bounds__(256) void final_kernel(const float* __restrict__ xo,
    const float* __restrict__ mlp_w, const float* __restrict__ mlp_b,
    float* __restrict__ out, int total) {
  __shared__ float wsh[40 * 65];
  __shared__ float bsh[40];
  for (int i = threadIdx.x; i < 40 * 64; i += 256) wsh[(i >> 6) * 65 + (i & 63)] = mlp_w[i];
  if (threadIdx.x < 40) bsh[threadIdx.x] = mlp_b[threadIdx.x];
  __syncthreads();
  int idx = blockIdx.x * 256 + threadIdx.x;
  if (idx >= total) return;
  int n = idx / 40, c = idx - n * 40;
  const float* xr = xo + (size_t)n * 64;
  const float* wr = wsh + c * 65;
  float acc = bsh[c];
#pragma unroll
  for (int j = 0; j < 64; ++j) acc += xr[j] * wr[j];
  out[idx] = acc;
}

extern "C" void kernel_launch(void* const* d_in, const int* in_sizes, int n_in,
                              void* d_out, int out_size, void* d_ws, size_t ws_size,
                              hipStream_t stream) {
  (void)n_in; (void)out_size; (void)ws_size;
  const float* x  = (const float*)d_in[0];
  const int*   ei = (const int*)d_in[1];
  const float* W  = (const float*)d_in[2];
  const float* a  = (const float*)d_in[3];
  const float* Wo = (const float*)d_in[4];
  const float* ao = (const float*)d_in[5];
  const float* mw = (const float*)d_in[6];
  const float* mb = (const float*)d_in[7];
  float* out = (float*)d_out;

  const int N = NN;
  const int E = in_sizes[1] / 2;
  const int* src = ei;
  const int* dst = ei + E;

  char* ws = (char*)d_ws;
  size_t off = 0;
  auto alloc = [&](size_t bytes) {
    char* p = ws + off;
    off = (off + bytes + 255) & ~(size_t)255;
    return p;
  };
  unsigned short* h1b = (unsigned short*)alloc((size_t)N * 512 * 2); // 51.2 MB, [N][512]
  float* ss1     = (float*)alloc((size_t)N * 8 * 4);                 // [N][8]
  float* sd1     = (float*)alloc((size_t)N * 8 * 4);
  float* xc      = (float*)alloc((size_t)N * 512 * 4);               // 102.4 MB fp32
  unsigned short* h2b = (unsigned short*)alloc((size_t)N * 64 * 2);  // [N][64]
  float* ss2     = (float*)alloc((size_t)N * 4);
  float* sd2     = (float*)alloc((size_t)N * 4);
  float* xo      = (float*)alloc((size_t)N * 64 * 4);
  int*   row_ptr = (int*)  alloc((size_t)(N + 1) * 4);
  int*   nxt     = (int*)  alloc((size_t)N * 4);
  int*   cnt     = (int*)  alloc((size_t)N * 4);
  int*   tmp     = (int*)  alloc((size_t)N * 4);
  int*   bsum    = (int*)  alloc(64 * 4);
  int*   boffs   = (int*)  alloc(64 * 4);
  int*   colv    = (int*)  alloc((size_t)E * 4);

  int eb = (E + 255) / 256;
  int nb1024 = (N + 1023) / 1024;   // 49

  hipMemsetAsync(cnt, 0, (size_t)N * 4, stream);
  hipLaunchKernelGGL(hist_kernel, dim3(eb), dim3(256), 0, stream, src, cnt, E);
  hipLaunchKernelGGL(scan_blocks_kernel, dim3(nb1024), dim3(1024), 0, stream, cnt, tmp, bsum, N);
  hipLaunchKernelGGL(scan_top_kernel, dim3(1), dim3(64), 0, stream, bsum, boffs, nb1024);
  hipLaunchKernelGGL(scan_apply_kernel, dim3(nb1024), dim3(1024), 0, stream, tmp, boffs, row_ptr, nxt, N, E);
  hipLaunchKernelGGL(scatter_kernel, dim3(eb), dim3(256), 0, stream, src, dst, nxt, colv, E);

  // layer 1: h1b bf16 [N][512] + scores [N][8], then aggregate -> xc fp32 [N][512]
  hipLaunchKernelGGL(gemm_fused_kernel, dim3((N + 127) / 128, HH), dim3(256), 0, stream,
                     x, W, a, h1b, ss1, sd1, N, 256, 512, 8);
  hipLaunchKernelGGL(agg1_kernel, dim3((N + 3) / 4), dim3(256), 0, stream,
                     h1b, ss1, sd1, row_ptr, colv, xc, N);

  // layer 2: h2b bf16 [N][64] + scores [N], aggregate -> xo
  hipLaunchKernelGGL(gemm_fused_kernel, dim3((N + 127) / 128, 1), dim3(256), 0, stream,
                     xc, Wo, ao, h2b, ss2, sd2, N, 512, 64, 1);
  hipLaunchKernelGGL(agg2_kernel, dim3((N + 3) / 4), dim3(256), 0, stream,
                     h2b, ss2, sd2, row_ptr, colv, xo, N);

  // classifier
  hipLaunchKernelGGL(final_kernel, dim3((N * 40 + 255) / 256), dim3(256), 0, stream,
                     xo, mw, mb, out, N * 40);
}

// Round 5
// 494.128 us; speedup vs baseline: 1.3513x; 1.3067x over previous
//
#include <hip/hip_runtime.h>

#define NN 50000
#define HH 8
#define ALPHA 0.2f
#define NPAD 50048   // NN rounded up to 128

typedef short short8 __attribute__((ext_vector_type(8)));
typedef float f32x4 __attribute__((ext_vector_type(4)));

__device__ __forceinline__ float elu_f(float x) {
  return x > 0.f ? x : __expf(x) - 1.f;
}

__device__ __forceinline__ unsigned short f2bf(float f) {
  unsigned int u = __float_as_uint(f);
  unsigned int r = (u + 0x7fffu + ((u >> 16) & 1u)) >> 16;
  return (unsigned short)r;
}

// ---------------- dtype prep ----------------
__global__ void cvt_x_kernel(const float* __restrict__ x, unsigned short* __restrict__ xb,
                             int total4) {
  int i = blockIdx.x * 256 + threadIdx.x;
  if (i >= total4) return;
  float4 v = ((const float4*)x)[i];
  ushort4 o;
  o.x = f2bf(v.x); o.y = f2bf(v.y); o.z = f2bf(v.z); o.w = f2bf(v.w);
  ((ushort4*)xb)[i] = o;
}

// W [H][K][64] fp32 -> Wt [H][64][K] bf16
__global__ void cvt_w_kernel(const float* __restrict__ W, unsigned short* __restrict__ Wt,
                             int K, int total) {
  int tid = blockIdx.x * 256 + threadIdx.x;
  if (tid >= total) return;
  int h = tid / (K * 64);
  int rem = tid - h * K * 64;
  int k = rem >> 6, c = rem & 63;
  Wt[((size_t)h * 64 + c) * K + k] = f2bf(W[tid]);
}

// ---------------- CSR build ----------------
__global__ void hist_kernel(const int* __restrict__ src, int* __restrict__ cnt, int E) {
  int e = blockIdx.x * blockDim.x + threadIdx.x;
  if (e < E) atomicAdd(&cnt[src[e]], 1);
}

__global__ __launch_bounds__(1024) void scan_blocks_kernel(const int* __restrict__ cnt,
    int* __restrict__ tmp, int* __restrict__ bsum, int n) {
  __shared__ int sh[1024];
  int i = blockIdx.x * 1024 + threadIdx.x;
  int v = (i < n) ? cnt[i] : 0;
  sh[threadIdx.x] = v;
  __syncthreads();
  for (int off = 1; off < 1024; off <<= 1) {
    int t = (threadIdx.x >= off) ? sh[threadIdx.x - off] : 0;
    __syncthreads();
    sh[threadIdx.x] += t;
    __syncthreads();
  }
  if (i < n) tmp[i] = sh[threadIdx.x] - v;
  if (threadIdx.x == 1023) bsum[blockIdx.x] = sh[1023];
}

__global__ __launch_bounds__(64) void scan_top_kernel(const int* __restrict__ bsum,
    int* __restrict__ boffs, int nb) {
  int L = threadIdx.x;
  int v = (L < nb) ? bsum[L] : 0;
  int incl = v;
#pragma unroll
  for (int off = 1; off < 64; off <<= 1) {
    int t = __shfl_up(incl, off, 64);
    if (L >= off) incl += t;
  }
  if (L < nb) boffs[L] = incl - v;
}

__global__ __launch_bounds__(1024) void scan_apply_kernel(const int* __restrict__ tmp,
    const int* __restrict__ boffs, int* __restrict__ row_ptr, int* __restrict__ nxt,
    int n, int E) {
  int i = blockIdx.x * 1024 + threadIdx.x;
  if (i < n) {
    int s = tmp[i] + boffs[blockIdx.x];
    row_ptr[i] = s;
    nxt[i] = s;
  }
  if (i == 0) row_ptr[n] = E;
}

__global__ void scatter_kernel(const int* __restrict__ src, const int* __restrict__ dst,
                               int* __restrict__ nxt, int* __restrict__ col, int E) {
  int e = blockIdx.x * blockDim.x + threadIdx.x;
  if (e < E) {
    int p = atomicAdd(&nxt[src[e]], 1);
    col[p] = dst[e];
  }
}

// ---------------- bf16 MFMA GEMM + score epilogue ----------------
// A bf16 [NPAD][K] (k-contig); Bt bf16 [y][64][K]; out table bf16 Cout[r*tab_stride+y*64+c];
// scores fp32 ss/sd[r*score_stride+y].  MT = m-tiles per wave (block rows = 64*MT).
template <int MT>
__global__ __launch_bounds__(256) void mfma_gemm_kernel(
    const unsigned short* __restrict__ A, const unsigned short* __restrict__ Bt,
    const float* __restrict__ Aatt, unsigned short* __restrict__ Cout,
    float* __restrict__ ss, float* __restrict__ sd,
    int N, int K, int tab_stride, int score_stride) {
  extern __shared__ unsigned short Bs[];   // [64][K+8]
  const int y = blockIdx.y;
  const int Kp = K + 8;

  // stage B tile (whole [64][K]) to LDS
  {
    const unsigned short* Bsrc = Bt + (size_t)y * 64 * K;
    int nchunk = 64 * (K >> 3);
    for (int c = threadIdx.x; c < nchunk; c += 256) {
      int n = c / (K >> 3);
      int kq = (c - n * (K >> 3)) << 3;
      *(uint4*)&Bs[n * Kp + kq] = *(const uint4*)(Bsrc + (size_t)n * K + kq);
    }
  }
  __syncthreads();

  int w = threadIdx.x >> 6, L = threadIdx.x & 63;
  int quad = L >> 4, l16 = L & 15;
  int m0 = blockIdx.x * (64 * MT) + w * (16 * MT);

  f32x4 acc[MT][4];
#pragma unroll
  for (int mt = 0; mt < MT; ++mt)
#pragma unroll
    for (int nt = 0; nt < 4; ++nt) acc[mt][nt] = (f32x4)(0.f);

  const unsigned short* Arow[MT];
#pragma unroll
  for (int mt = 0; mt < MT; ++mt)
    Arow[mt] = A + (size_t)(m0 + mt * 16 + l16) * K + quad * 8;

  short8 a_cur[MT];
#pragma unroll
  for (int mt = 0; mt < MT; ++mt) a_cur[mt] = *(const short8*)(Arow[mt]);

  for (int k0 = 0; k0 < K; k0 += 32) {
    short8 a_nxt[MT];
    if (k0 + 32 < K) {
#pragma unroll
      for (int mt = 0; mt < MT; ++mt) a_nxt[mt] = *(const short8*)(Arow[mt] + k0 + 32);
    }
#pragma unroll
    for (int nt = 0; nt < 4; ++nt) {
      short8 b = *(const short8*)&Bs[(l16 + 16 * nt) * Kp + k0 + quad * 8];
#pragma unroll
      for (int mt = 0; mt < MT; ++mt)
        acc[mt][nt] = __builtin_amdgcn_mfma_f32_16x16x32_bf16(a_cur[mt], b, acc[mt][nt], 0, 0, 0);
    }
#pragma unroll
    for (int mt = 0; mt < MT; ++mt) a_cur[mt] = a_nxt[mt];
  }

  // epilogue: scores (fp32 acc) + bf16 table
  float as[4], ad[4];
#pragma unroll
  for (int nt = 0; nt < 4; ++nt) {
    as[nt] = Aatt[y * 128 + l16 + 16 * nt];
    ad[nt] = Aatt[y * 128 + 64 + l16 + 16 * nt];
  }
#pragma unroll
  for (int mt = 0; mt < MT; ++mt) {
#pragma unroll
    for (int reg = 0; reg < 4; ++reg) {
      float p = 0.f, q = 0.f;
#pragma unroll
      for (int nt = 0; nt < 4; ++nt) {
        p += acc[mt][nt][reg] * as[nt];
        q += acc[mt][nt][reg] * ad[nt];
      }
#pragma unroll
      for (int off = 1; off < 16; off <<= 1) {
        p += __shfl_xor(p, off, 64);
        q += __shfl_xor(q, off, 64);
      }
      int row = m0 + mt * 16 + quad * 4 + reg;
      if (l16 == 0 && row < N) {
        ss[(size_t)row * score_stride + y] = p;
        sd[(size_t)row * score_stride + y] = q;
      }
    }
#pragma unroll
    for (int reg = 0; reg < 4; ++reg) {
      int row = m0 + mt * 16 + quad * 4 + reg;
      if (row < N) {
#pragma unroll
        for (int nt = 0; nt < 4; ++nt)
          Cout[(size_t)row * tab_stride + y * 64 + l16 + 16 * nt] = f2bf(acc[mt][nt][reg]);
      }
    }
  }
}

// ---------------- layer-1 aggregation: wave per node, all 8 heads fused ----------------
// table: bf16 [N][512]; ss/sd: fp32 [N][8]; out xc bf16 [NPAD][512].
__global__ __launch_bounds__(256) void agg1_kernel(const unsigned short* __restrict__ table,
    const float* __restrict__ ss, const float* __restrict__ sd,
    const int* __restrict__ row_ptr, const int* __restrict__ col,
    unsigned short* __restrict__ xc, int N) {
  int wid = threadIdx.x >> 6, L = threadIdx.x & 63;
  int n = blockIdx.x * 4 + wid;
  if (n >= N) return;
  int h = L >> 3;
  int b = L & 7;
  int srcsel = h << 3;
  float ssn = ss[n * 8 + h];
  int k0 = row_ptr[n], deg = row_ptr[n + 1] - k0;
  float acc[8];
#pragma unroll
  for (int t = 0; t < 8; ++t) acc[t] = 0.f;
  float rs = 0.f;

  for (int c0 = 0; c0 < deg; c0 += 64) {
    int j = c0 + L;
    int d_l = (j < deg) ? col[k0 + j] : 0;
    int m = min(64, deg - c0);
    for (int g = 0; g < m; g += 8) {
      int eoff = g + b;
      int de = __shfl(d_l, eoff, 64);
      float sv = sd[(size_t)de * 8 + h];
      float s = ssn + sv;
      float e = __expf(-fmaxf(s, ALPHA * s));
      if (eoff >= m) e = 0.f;
      rs += e;
      int gm = min(8, m - g);
      int d0 = __builtin_amdgcn_readlane(d_l, g);
      uint4 rv = *((const uint4*)(table + (size_t)d0 * 512) + L);
      for (int jj = 0; jj < gm; ++jj) {
        uint4 cur = rv;
        if (jj + 1 < gm) {
          int dn = __builtin_amdgcn_readlane(d_l, g + jj + 1);
          rv = *((const uint4*)(table + (size_t)dn * 512) + L);
        }
        float ew = __shfl(e, srcsel + jj, 64);
        const unsigned int* up = (const unsigned int*)&cur;
#pragma unroll
        for (int w = 0; w < 4; ++w) {
          acc[2 * w]     += ew * __uint_as_float(up[w] << 16);
          acc[2 * w + 1] += ew * __uint_as_float(up[w] & 0xffff0000u);
        }
      }
    }
  }
  rs += __shfl_xor(rs, 1, 64);
  rs += __shfl_xor(rs, 2, 64);
  rs += __shfl_xor(rs, 4, 64);
  float inv = 1.f / rs;
  short8 pk;
#pragma unroll
  for (int t = 0; t < 8; ++t) pk[t] = (short)f2bf(elu_f(acc[t] * inv));
  *(short8*)(xc + (size_t)n * 512 + L * 8) = pk;
}

// ---------------- layer-2 aggregation ----------------
__global__ __launch_bounds__(256) void agg2_kernel(const unsigned short* __restrict__ table,
    const float* __restrict__ ss, const float* __restrict__ sd,
    const int* __restrict__ row_ptr, const int* __restrict__ col,
    float* __restrict__ xo, int N) {
  int wid = threadIdx.x >> 6, L = threadIdx.x & 63;
  int n = blockIdx.x * 4 + wid;
  if (n >= N) return;
  float ssn = ss[n];
  int k0 = row_ptr[n], deg = row_ptr[n + 1] - k0;
  float acc = 0.f, rs = 0.f;
  const char* base = (const char*)table;

  for (int c0 = 0; c0 < deg; c0 += 64) {
    int j = c0 + L;
    int d_l = 0;
    float e_l = 0.f;
    if (j < deg) {
      d_l = col[k0 + j];
      float s = ssn + sd[d_l];
      e_l = __expf(-fmaxf(s, ALPHA * s));
    }
    rs += e_l;
    int m = min(64, deg - c0);
    int off_l = d_l << 7;
    int so = __builtin_amdgcn_readlane(off_l, 0);
    unsigned hv = *(const unsigned short*)(base + so + L * 2);
    for (int jj = 0; jj < m; ++jj) {
      unsigned cur = hv;
      if (jj + 1 < m) {
        so = __builtin_amdgcn_readlane(off_l, jj + 1);
        hv = *(const unsigned short*)(base + so + L * 2);
      }
      float ew = __uint_as_float(
          (unsigned)__builtin_amdgcn_readlane(__float_as_uint(e_l), jj));
      acc += ew * __uint_as_float(cur << 16);
    }
  }
#pragma unroll
  for (int off = 1; off < 64; off <<= 1) rs += __shfl_xor(rs, off, 64);
  xo[(size_t)n * 64 + L] = elu_f(acc / rs);
}

// ---------------- final classifier ----------------
__global__ __launch_bounds__(256) void final_kernel(const float* __restrict__ xo,
    const float* __restrict__ mlp_w, const float* __restrict__ mlp_b,
    float* __restrict__ out, int total) {
  __shared__ float wsh[40 * 65];
  __shared__ float bsh[40];
  for (int i = threadIdx.x; i < 40 * 64; i += 256) wsh[(i >> 6) * 65 + (i & 63)] = mlp_w[i];
  if (threadIdx.x < 40) bsh[threadIdx.x] = mlp_b[threadIdx.x];
  __syncthreads();
  int idx = blockIdx.x * 256 + threadIdx.x;
  if (idx >= total) return;
  int n = idx / 40, c = idx - n * 40;
  const float* xr = xo + (size_t)n * 64;
  const float* wr = wsh + c * 65;
  float acc = bsh[c];
#pragma unroll
  for (int j = 0; j < 64; ++j) acc += xr[j] * wr[j];
  out[idx] = acc;
}

extern "C" void kernel_launch(void* const* d_in, const int* in_sizes, int n_in,
                              void* d_out, int out_size, void* d_ws, size_t ws_size,
                              hipStream_t stream) {
  (void)n_in; (void)out_size; (void)ws_size;
  const float* x  = (const float*)d_in[0];
  const int*   ei = (const int*)d_in[1];
  const float* W  = (const float*)d_in[2];
  const float* a  = (const float*)d_in[3];
  const float* Wo = (const float*)d_in[4];
  const float* ao = (const float*)d_in[5];
  const float* mw = (const float*)d_in[6];
  const float* mb = (const float*)d_in[7];
  float* out = (float*)d_out;

  const int N = NN;
  const int E = in_sizes[1] / 2;
  const int* src = ei;
  const int* dst = ei + E;

  char* ws = (char*)d_ws;
  size_t off = 0;
  auto alloc = [&](size_t bytes) {
    char* p = ws + off;
    off = (off + bytes + 255) & ~(size_t)255;
    return p;
  };
  unsigned short* xb  = (unsigned short*)alloc((size_t)NPAD * 256 * 2); // 25.6 MB
  unsigned short* Wt  = (unsigned short*)alloc((size_t)HH * 64 * 256 * 2);
  unsigned short* Wot = (unsigned short*)alloc((size_t)64 * 512 * 2);
  unsigned short* h1b = (unsigned short*)alloc((size_t)N * 512 * 2);    // 51.2 MB
  float* ss1     = (float*)alloc((size_t)N * 8 * 4);
  float* sd1     = (float*)alloc((size_t)N * 8 * 4);
  unsigned short* xc = (unsigned short*)alloc((size_t)NPAD * 512 * 2);  // 51.25 MB
  unsigned short* h2b = (unsigned short*)alloc((size_t)N * 64 * 2);
  float* ss2     = (float*)alloc((size_t)N * 4);
  float* sd2     = (float*)alloc((size_t)N * 4);
  float* xo      = (float*)alloc((size_t)N * 64 * 4);
  int*   row_ptr = (int*)  alloc((size_t)(N + 1) * 4);
  int*   nxt     = (int*)  alloc((size_t)N * 4);
  int*   cnt     = (int*)  alloc((size_t)N * 4);
  int*   tmp     = (int*)  alloc((size_t)N * 4);
  int*   bsum    = (int*)  alloc(64 * 4);
  int*   boffs   = (int*)  alloc(64 * 4);
  int*   colv    = (int*)  alloc((size_t)E * 4);

  int eb = (E + 255) / 256;
  int nb1024 = (N + 1023) / 1024;   // 49

  // dtype prep
  hipLaunchKernelGGL(cvt_x_kernel, dim3((N * 256 / 4 + 255) / 256), dim3(256), 0, stream,
                     x, xb, N * 256 / 4);
  hipLaunchKernelGGL(cvt_w_kernel, dim3((HH * 256 * 64 + 255) / 256), dim3(256), 0, stream,
                     W, Wt, 256, HH * 256 * 64);
  hipLaunchKernelGGL(cvt_w_kernel, dim3((512 * 64 + 255) / 256), dim3(256), 0, stream,
                     Wo, Wot, 512, 512 * 64);

  // CSR
  hipMemsetAsync(cnt, 0, (size_t)N * 4, stream);
  hipLaunchKernelGGL(hist_kernel, dim3(eb), dim3(256), 0, stream, src, cnt, E);
  hipLaunchKernelGGL(scan_blocks_kernel, dim3(nb1024), dim3(1024), 0, stream, cnt, tmp, bsum, N);
  hipLaunchKernelGGL(scan_top_kernel, dim3(1), dim3(64), 0, stream, bsum, boffs, nb1024);
  hipLaunchKernelGGL(scan_apply_kernel, dim3(nb1024), dim3(1024), 0, stream, tmp, boffs, row_ptr, nxt, N, E);
  hipLaunchKernelGGL(scatter_kernel, dim3(eb), dim3(256), 0, stream, src, dst, nxt, colv, E);

  // layer 1: MFMA GEMM (128-row blocks, 8 heads) -> h1b + scores; aggregate -> xc (bf16)
  hipLaunchKernelGGL((mfma_gemm_kernel<2>), dim3(NPAD / 128, HH), dim3(256),
                     64 * (256 + 8) * 2, stream,
                     xb, Wt, a, h1b, ss1, sd1, N, 256, 512, 8);
  hipLaunchKernelGGL(agg1_kernel, dim3((N + 3) / 4), dim3(256), 0, stream,
                     h1b, ss1, sd1, row_ptr, colv, xc, N);

  // layer 2: MFMA GEMM (64-row blocks) -> h2b + scores; aggregate -> xo
  hipLaunchKernelGGL((mfma_gemm_kernel<1>), dim3(NPAD / 64, 1), dim3(256),
                     64 * (512 + 8) * 2, stream,
                     xc, Wot, ao, h2b, ss2, sd2, N, 512, 64, 1);
  hipLaunchKernelGGL(agg2_kernel, dim3((N + 3) / 4), dim3(256), 0, stream,
                     h2b, ss2, sd2, row_ptr, colv, xo, N);

  // classifier
  hipLaunchKernelGGL(final_kernel, dim3((N * 40 + 255) / 256), dim3(256), 0, stream,
                     xo, mw, mb, out, N * 40);
}

// Round 6
// 457.235 us; speedup vs baseline: 1.4604x; 1.0807x over previous
//
#include <hip/hip_runtime.h>

#define NN 50000
#define HH 8
#define ALPHA 0.2f
#define NPAD 50048   // NN rounded up to 128

typedef short short8 __attribute__((ext_vector_type(8)));
typedef float f32x4 __attribute__((ext_vector_type(4)));

__device__ __forceinline__ float elu_f(float x) {
  return x > 0.f ? x : __expf(x) - 1.f;
}

__device__ __forceinline__ unsigned short f2bf(float f) {
  unsigned int u = __float_as_uint(f);
  unsigned int r = (u + 0x7fffu + ((u >> 16) & 1u)) >> 16;
  return (unsigned short)r;
}

// ---------------- fused dtype prep ----------------
// part0: x fp32 -> xb bf16 (float4 granular); part1: W [H][256][64] -> Wt [H][64][256];
// part2: Wo [512][64] -> Wot [64][512].
__global__ void cvt_all_kernel(const float* __restrict__ x, unsigned short* __restrict__ xb,
                               const float* __restrict__ W, unsigned short* __restrict__ Wt,
                               const float* __restrict__ Wo, unsigned short* __restrict__ Wot,
                               int n4x) {
  int tid = blockIdx.x * 256 + threadIdx.x;
  if (tid < n4x) {
    float4 v = ((const float4*)x)[tid];
    ushort4 o;
    o.x = f2bf(v.x); o.y = f2bf(v.y); o.z = f2bf(v.z); o.w = f2bf(v.w);
    ((ushort4*)xb)[tid] = o;
    return;
  }
  int t1 = tid - n4x;
  if (t1 < HH * 256 * 64) {
    int h = t1 / (256 * 64);
    int rem = t1 - h * 256 * 64;
    int k = rem >> 6, c = rem & 63;
    Wt[((size_t)h * 64 + c) * 256 + k] = f2bf(W[t1]);
    return;
  }
  int t2 = t1 - HH * 256 * 64;
  if (t2 < 512 * 64) {
    int k = t2 >> 6, c = t2 & 63;
    Wot[(size_t)c * 512 + k] = f2bf(Wo[t2]);
  }
}

// ---------------- CSR build ----------------
__global__ void hist_kernel(const int* __restrict__ src, int* __restrict__ cnt, int E) {
  int e = blockIdx.x * blockDim.x + threadIdx.x;
  if (e < E) atomicAdd(&cnt[src[e]], 1);
}

__global__ __launch_bounds__(1024) void scan_blocks_kernel(const int* __restrict__ cnt,
    int* __restrict__ tmp, int* __restrict__ bsum, int n) {
  __shared__ int sh[1024];
  int i = blockIdx.x * 1024 + threadIdx.x;
  int v = (i < n) ? cnt[i] : 0;
  sh[threadIdx.x] = v;
  __syncthreads();
  for (int off = 1; off < 1024; off <<= 1) {
    int t = (threadIdx.x >= off) ? sh[threadIdx.x - off] : 0;
    __syncthreads();
    sh[threadIdx.x] += t;
    __syncthreads();
  }
  if (i < n) tmp[i] = sh[threadIdx.x] - v;
  if (threadIdx.x == 1023) bsum[blockIdx.x] = sh[1023];
}

__global__ __launch_bounds__(64) void scan_top_kernel(const int* __restrict__ bsum,
    int* __restrict__ boffs, int nb) {
  int L = threadIdx.x;
  int v = (L < nb) ? bsum[L] : 0;
  int incl = v;
#pragma unroll
  for (int off = 1; off < 64; off <<= 1) {
    int t = __shfl_up(incl, off, 64);
    if (L >= off) incl += t;
  }
  if (L < nb) boffs[L] = incl - v;
}

__global__ __launch_bounds__(1024) void scan_apply_kernel(const int* __restrict__ tmp,
    const int* __restrict__ boffs, int* __restrict__ row_ptr, int* __restrict__ nxt,
    int n, int E) {
  int i = blockIdx.x * 1024 + threadIdx.x;
  if (i < n) {
    int s = tmp[i] + boffs[blockIdx.x];
    row_ptr[i] = s;
    nxt[i] = s;
  }
  if (i == 0) row_ptr[n] = E;
}

__global__ void scatter_kernel(const int* __restrict__ src, const int* __restrict__ dst,
                               int* __restrict__ nxt, int* __restrict__ col, int E) {
  int e = blockIdx.x * blockDim.x + threadIdx.x;
  if (e < E) {
    int p = atomicAdd(&nxt[src[e]], 1);
    col[p] = dst[e];
  }
}

// ---------------- layer-1 MFMA GEMM: A read once, loop over 8 heads ----------------
// A bf16 [NPAD][256]; Bt bf16 [8][64][256]; out h1b bf16 [N][512]; scores [N][8].
__global__ __launch_bounds__(256) void mfma_gemm1_kernel(
    const unsigned short* __restrict__ A, const unsigned short* __restrict__ Bt,
    const float* __restrict__ Aatt, unsigned short* __restrict__ Cout,
    float* __restrict__ ss, float* __restrict__ sd, int N) {
  __shared__ unsigned short Bs[64][264];   // 33.8 KB, +8 pad
  int w = threadIdx.x >> 6, L = threadIdx.x & 63;
  int quad = L >> 4, l16 = L & 15;
  int m0 = blockIdx.x * 64;
  int myrow = m0 + w * 16 + l16;

  // A fragments for the whole K=256, loaded once: 8 x short8 = 32 VGPRs
  const unsigned short* Ar = A + (size_t)myrow * 256 + quad * 8;
  short8 areg[8];
#pragma unroll
  for (int ks = 0; ks < 8; ++ks) areg[ks] = *(const short8*)(Ar + ks * 32);

  for (int y = 0; y < HH; ++y) {
    __syncthreads();                       // previous head's Bs reads done
    {
      const unsigned short* Bsrc = Bt + (size_t)y * 64 * 256;
      for (int c = threadIdx.x; c < 2048; c += 256) {   // 64 rows x 32 chunks
        int n = c >> 5;
        int kq = (c & 31) << 3;
        *(uint4*)&Bs[n][kq] = *(const uint4*)(Bsrc + (size_t)n * 256 + kq);
      }
    }
    __syncthreads();

    f32x4 acc[4];
#pragma unroll
    for (int nt = 0; nt < 4; ++nt) acc[nt] = (f32x4)(0.f);
#pragma unroll
    for (int ks = 0; ks < 8; ++ks) {
#pragma unroll
      for (int nt = 0; nt < 4; ++nt) {
        short8 b = *(const short8*)&Bs[l16 + 16 * nt][ks * 32 + quad * 8];
        acc[nt] = __builtin_amdgcn_mfma_f32_16x16x32_bf16(areg[ks], b, acc[nt], 0, 0, 0);
      }
    }

    // epilogue head y
    float as[4], ad[4];
#pragma unroll
    for (int nt = 0; nt < 4; ++nt) {
      as[nt] = Aatt[y * 128 + l16 + 16 * nt];
      ad[nt] = Aatt[y * 128 + 64 + l16 + 16 * nt];
    }
#pragma unroll
    for (int reg = 0; reg < 4; ++reg) {
      float p = 0.f, q = 0.f;
#pragma unroll
      for (int nt = 0; nt < 4; ++nt) {
        p += acc[nt][reg] * as[nt];
        q += acc[nt][reg] * ad[nt];
      }
#pragma unroll
      for (int off = 1; off < 16; off <<= 1) {
        p += __shfl_xor(p, off, 64);
        q += __shfl_xor(q, off, 64);
      }
      int row = m0 + w * 16 + quad * 4 + reg;
      if (l16 == 0 && row < N) {
        ss[(size_t)row * 8 + y] = p;
        sd[(size_t)row * 8 + y] = q;
      }
    }
#pragma unroll
    for (int reg = 0; reg < 4; ++reg) {
      int row = m0 + w * 16 + quad * 4 + reg;
      if (row < N) {
#pragma unroll
        for (int nt = 0; nt < 4; ++nt)
          Cout[(size_t)row * 512 + y * 64 + l16 + 16 * nt] = f2bf(acc[nt][reg]);
      }
    }
  }
}

// ---------------- layer-2 MFMA GEMM (B staged whole in LDS) ----------------
__global__ __launch_bounds__(256) void mfma_gemm2_kernel(
    const unsigned short* __restrict__ A, const unsigned short* __restrict__ Bt,
    const float* __restrict__ Aatt, unsigned short* __restrict__ Cout,
    float* __restrict__ ss, float* __restrict__ sd, int N) {
  __shared__ unsigned short Bs[64][520];   // K=512 +8 pad, 66.6 KB
  {
    for (int c = threadIdx.x; c < 4096; c += 256) {     // 64 rows x 64 chunks
      int n = c >> 6;
      int kq = (c & 63) << 3;
      *(uint4*)&Bs[n][kq] = *(const uint4*)(Bt + (size_t)n * 512 + kq);
    }
  }
  __syncthreads();

  int w = threadIdx.x >> 6, L = threadIdx.x & 63;
  int quad = L >> 4, l16 = L & 15;
  int m0 = blockIdx.x * 64;
  int myrow = m0 + w * 16 + l16;
  const unsigned short* Ar = A + (size_t)myrow * 512 + quad * 8;

  f32x4 acc[4];
#pragma unroll
  for (int nt = 0; nt < 4; ++nt) acc[nt] = (f32x4)(0.f);

  short8 a_cur = *(const short8*)(Ar);
  for (int k0 = 0; k0 < 512; k0 += 32) {
    short8 a_nxt;
    if (k0 + 32 < 512) a_nxt = *(const short8*)(Ar + k0 + 32);
#pragma unroll
    for (int nt = 0; nt < 4; ++nt) {
      short8 b = *(const short8*)&Bs[l16 + 16 * nt][k0 + quad * 8];
      acc[nt] = __builtin_amdgcn_mfma_f32_16x16x32_bf16(a_cur, b, acc[nt], 0, 0, 0);
    }
    a_cur = a_nxt;
  }

  float as[4], ad[4];
#pragma unroll
  for (int nt = 0; nt < 4; ++nt) {
    as[nt] = Aatt[l16 + 16 * nt];
    ad[nt] = Aatt[64 + l16 + 16 * nt];
  }
#pragma unroll
  for (int reg = 0; reg < 4; ++reg) {
    float p = 0.f, q = 0.f;
#pragma unroll
    for (int nt = 0; nt < 4; ++nt) {
      p += acc[nt][reg] * as[nt];
      q += acc[nt][reg] * ad[nt];
    }
#pragma unroll
    for (int off = 1; off < 16; off <<= 1) {
      p += __shfl_xor(p, off, 64);
      q += __shfl_xor(q, off, 64);
    }
    int row = m0 + w * 16 + quad * 4 + reg;
    if (l16 == 0 && row < N) { ss[row] = p; sd[row] = q; }
  }
#pragma unroll
  for (int reg = 0; reg < 4; ++reg) {
    int row = m0 + w * 16 + quad * 4 + reg;
    if (row < N) {
#pragma unroll
      for (int nt = 0; nt < 4; ++nt)
        Cout[(size_t)row * 64 + l16 + 16 * nt] = f2bf(acc[nt][reg]);
    }
  }
}

// ---------------- layer-1 aggregation: wave/node, 8 heads fused, 8-wide MLP ----------------
__global__ __launch_bounds__(256) void agg1_kernel(const unsigned short* __restrict__ table,
    const float* __restrict__ ss, const float* __restrict__ sd,
    const int* __restrict__ row_ptr, const int* __restrict__ col,
    unsigned short* __restrict__ xc, int N) {
  int wid = threadIdx.x >> 6, L = threadIdx.x & 63;
  int n = blockIdx.x * 4 + wid;
  if (n >= N) return;
  int h = L >> 3;
  int b = L & 7;
  int srcsel = h << 3;
  float ssn = ss[n * 8 + h];
  int k0 = row_ptr[n], deg = row_ptr[n + 1] - k0;
  float acc[8];
#pragma unroll
  for (int t = 0; t < 8; ++t) acc[t] = 0.f;
  float rs = 0.f;

  for (int c0 = 0; c0 < deg; c0 += 64) {
    int j = c0 + L;
    int d_l = (j < deg) ? col[k0 + j] : 0;
    int m = min(64, deg - c0);
    for (int g = 0; g < m; g += 8) {
      // e-phase: lane (h'*8+b') computes e for (edge g+b', head h')
      int eoff = g + b;
      int de = __shfl(d_l, eoff, 64);
      float s = ssn + sd[(size_t)de * 8 + h];
      float e = __expf(-fmaxf(s, ALPHA * s));
      if (eoff >= m) e = 0.f;
      rs += e;
      int gm = min(8, m - g);
      // issue up to 8 independent row gathers before any FMA
      uint4 rv[8];
#pragma unroll
      for (int t = 0; t < 8; ++t) {
        if (t < gm) {
          int dg = __builtin_amdgcn_readlane(d_l, g + t);
          rv[t] = *((const uint4*)(table + (size_t)dg * 512) + L);
        }
      }
#pragma unroll
      for (int t = 0; t < 8; ++t) {
        if (t < gm) {
          float ew = __shfl(e, srcsel + t, 64);
          const unsigned int* up = (const unsigned int*)&rv[t];
#pragma unroll
          for (int v = 0; v < 4; ++v) {
            acc[2 * v]     += ew * __uint_as_float(up[v] << 16);
            acc[2 * v + 1] += ew * __uint_as_float(up[v] & 0xffff0000u);
          }
        }
      }
    }
  }
  rs += __shfl_xor(rs, 1, 64);
  rs += __shfl_xor(rs, 2, 64);
  rs += __shfl_xor(rs, 4, 64);
  float inv = 1.f / rs;
  short8 pk;
#pragma unroll
  for (int t = 0; t < 8; ++t) pk[t] = (short)f2bf(elu_f(acc[t] * inv));
  *(short8*)(xc + (size_t)n * 512 + L * 8) = pk;
}

// ---------------- layer-2 aggregation: 8-wide MLP ----------------
__global__ __launch_bounds__(256) void agg2_kernel(const unsigned short* __restrict__ table,
    const float* __restrict__ ss, const float* __restrict__ sd,
    const int* __restrict__ row_ptr, const int* __restrict__ col,
    float* __restrict__ xo, int N) {
  int wid = threadIdx.x >> 6, L = threadIdx.x & 63;
  int n = blockIdx.x * 4 + wid;
  if (n >= N) return;
  float ssn = ss[n];
  int k0 = row_ptr[n], deg = row_ptr[n + 1] - k0;
  float acc = 0.f, rs = 0.f;
  const char* base = (const char*)table;

  for (int c0 = 0; c0 < deg; c0 += 64) {
    int j = c0 + L;
    int d_l = 0;
    float e_l = 0.f;
    if (j < deg) {
      d_l = col[k0 + j];
      float s = ssn + sd[d_l];
      e_l = __expf(-fmaxf(s, ALPHA * s));
    }
    rs += e_l;
    int m = min(64, deg - c0);
    int off_l = d_l << 7;                  // row byte offset (64 * 2B)
    for (int g = 0; g < m; g += 8) {
      int gm = min(8, m - g);
      unsigned hv[8];
#pragma unroll
      for (int t = 0; t < 8; ++t) {
        if (t < gm) {
          int so = __builtin_amdgcn_readlane(off_l, g + t);
          hv[t] = *(const unsigned short*)(base + so + L * 2);
        }
      }
#pragma unroll
      for (int t = 0; t < 8; ++t) {
        if (t < gm) {
          float ew = __uint_as_float(
              (unsigned)__builtin_amdgcn_readlane(__float_as_uint(e_l), g + t));
          acc += ew * __uint_as_float(hv[t] << 16);
        }
      }
    }
  }
#pragma unroll
  for (int off = 1; off < 64; off <<= 1) rs += __shfl_xor(rs, off, 64);
  xo[(size_t)n * 64 + L] = elu_f(acc / rs);
}

// ---------------- final classifier ----------------
__global__ __launch_bounds__(256) void final_kernel(const float* __restrict__ xo,
    const float* __restrict__ mlp_w, const float* __restrict__ mlp_b,
    float* __restrict__ out, int total) {
  __shared__ float wsh[40 * 65];
  __shared__ float bsh[40];
  for (int i = threadIdx.x; i < 40 * 64; i += 256) wsh[(i >> 6) * 65 + (i & 63)] = mlp_w[i];
  if (threadIdx.x < 40) bsh[threadIdx.x] = mlp_b[threadIdx.x];
  __syncthreads();
  int idx = blockIdx.x * 256 + threadIdx.x;
  if (idx >= total) return;
  int n = idx / 40, c = idx - n * 40;
  const float* xr = xo + (size_t)n * 64;
  const float* wr = wsh + c * 65;
  float acc = bsh[c];
#pragma unroll
  for (int j = 0; j < 64; ++j) acc += xr[j] * wr[j];
  out[idx] = acc;
}

extern "C" void kernel_launch(void* const* d_in, const int* in_sizes, int n_in,
                              void* d_out, int out_size, void* d_ws, size_t ws_size,
                              hipStream_t stream) {
  (void)n_in; (void)out_size; (void)ws_size;
  const float* x  = (const float*)d_in[0];
  const int*   ei = (const int*)d_in[1];
  const float* W  = (const float*)d_in[2];
  const float* a  = (const float*)d_in[3];
  const float* Wo = (const float*)d_in[4];
  const float* ao = (const float*)d_in[5];
  const float* mw = (const float*)d_in[6];
  const float* mb = (const float*)d_in[7];
  float* out = (float*)d_out;

  const int N = NN;
  const int E = in_sizes[1] / 2;
  const int* src = ei;
  const int* dst = ei + E;

  char* ws = (char*)d_ws;
  size_t off = 0;
  auto alloc = [&](size_t bytes) {
    char* p = ws + off;
    off = (off + bytes + 255) & ~(size_t)255;
    return p;
  };
  unsigned short* xb  = (unsigned short*)alloc((size_t)NPAD * 256 * 2); // 25.6 MB
  unsigned short* Wt  = (unsigned short*)alloc((size_t)HH * 64 * 256 * 2);
  unsigned short* Wot = (unsigned short*)alloc((size_t)64 * 512 * 2);
  unsigned short* h1b = (unsigned short*)alloc((size_t)N * 512 * 2);    // 51.2 MB
  float* ss1     = (float*)alloc((size_t)N * 8 * 4);
  float* sd1     = (float*)alloc((size_t)N * 8 * 4);
  unsigned short* xc = (unsigned short*)alloc((size_t)NPAD * 512 * 2);  // 51.25 MB
  unsigned short* h2b = (unsigned short*)alloc((size_t)N * 64 * 2);
  float* ss2     = (float*)alloc((size_t)N * 4);
  float* sd2     = (float*)alloc((size_t)N * 4);
  float* xo      = (float*)alloc((size_t)N * 64 * 4);
  int*   row_ptr = (int*)  alloc((size_t)(N + 1) * 4);
  int*   nxt     = (int*)  alloc((size_t)N * 4);
  int*   cnt     = (int*)  alloc((size_t)N * 4);
  int*   tmp     = (int*)  alloc((size_t)N * 4);
  int*   bsum    = (int*)  alloc(64 * 4);
  int*   boffs   = (int*)  alloc(64 * 4);
  int*   colv    = (int*)  alloc((size_t)E * 4);

  int eb = (E + 255) / 256;
  int nb1024 = (N + 1023) / 1024;   // 49
  int n4x = N * 256 / 4;
  int cvt_total = n4x + HH * 256 * 64 + 512 * 64;

  // dtype prep (single fused kernel)
  hipLaunchKernelGGL(cvt_all_kernel, dim3((cvt_total + 255) / 256), dim3(256), 0, stream,
                     x, xb, W, Wt, Wo, Wot, n4x);

  // CSR
  hipMemsetAsync(cnt, 0, (size_t)N * 4, stream);
  hipLaunchKernelGGL(hist_kernel, dim3(eb), dim3(256), 0, stream, src, cnt, E);
  hipLaunchKernelGGL(scan_blocks_kernel, dim3(nb1024), dim3(1024), 0, stream, cnt, tmp, bsum, N);
  hipLaunchKernelGGL(scan_top_kernel, dim3(1), dim3(64), 0, stream, bsum, boffs, nb1024);
  hipLaunchKernelGGL(scan_apply_kernel, dim3(nb1024), dim3(1024), 0, stream, tmp, boffs, row_ptr, nxt, N, E);
  hipLaunchKernelGGL(scatter_kernel, dim3(eb), dim3(256), 0, stream, src, dst, nxt, colv, E);

  // layer 1
  hipLaunchKernelGGL(mfma_gemm1_kernel, dim3(NPAD / 64), dim3(256), 0, stream,
                     xb, Wt, a, h1b, ss1, sd1, N);
  hipLaunchKernelGGL(agg1_kernel, dim3((N + 3) / 4), dim3(256), 0, stream,
                     h1b, ss1, sd1, row_ptr, colv, xc, N);

  // layer 2
  hipLaunchKernelGGL(mfma_gemm2_kernel, dim3(NPAD / 64), dim3(256), 0, stream,
                     xc, Wot, ao, h2b, ss2, sd2, N);
  hipLaunchKernelGGL(agg2_kernel, dim3((N + 3) / 4), dim3(256), 0, stream,
                     h2b, ss2, sd2, row_ptr, colv, xo, N);

  // classifier
  hipLaunchKernelGGL(final_kernel, dim3((N * 40 + 255) / 256), dim3(256), 0, stream,
                     xo, mw, mb, out, N * 40);
}